// Round 1
// baseline (149.920 us; speedup 1.0000x reference)
//
#include <hip/hip_runtime.h>

// TimeVaryingDelayLine forward.
// y[n,c,t] = (1-frac)*xpad[n,c,pos-i0] + frac*xpad[n,c,pos-i0-1]
//   where xpad = concat(buffer, x) along time, pos = MAX_DELAY + t,
//   i0 = floor(dt), frac = dt - i0.
// We avoid materializing xpad: indices < MAX_DELAY read buffer, else x.

#define MAX_DELAY 40000
#define T_LEN     1000000

__global__ __launch_bounds__(256) void tvdl_kernel(
    const float* __restrict__ x,
    const float* __restrict__ dt,
    const float* __restrict__ buf,
    float* __restrict__ y,
    int n4_total)   // number of float4 elements
{
    int i = blockIdx.x * blockDim.x + threadIdx.x;
    if (i >= n4_total) return;
    int base = i << 2;                 // flat element index (multiple of 4)
    int nc = base / T_LEN;             // series index (T_LEN % 4 == 0 so all 4 share nc)
    int t0 = base - nc * T_LEN;        // time index of first element

    const float* __restrict__ xs = x   + (size_t)nc * T_LEN;
    const float* __restrict__ bs = buf + (size_t)nc * MAX_DELAY;

    float4 d = *reinterpret_cast<const float4*>(dt + base);

    float out[4];
    const float* dv = &d.x;
#pragma unroll
    for (int j = 0; j < 4; ++j) {
        float dvj  = dv[j];
        int   i0   = (int)dvj;             // dt >= 0, trunc == floor
        float frac = dvj - (float)i0;
        int   pos  = MAX_DELAY + t0 + j;
        int   ix0  = pos - i0;
        int   ix1  = ix0 - 1;
        if (ix1 < 0) ix1 = 0;
        float tap0 = (ix0 >= MAX_DELAY) ? xs[ix0 - MAX_DELAY] : bs[ix0];
        float tap1 = (ix1 >= MAX_DELAY) ? xs[ix1 - MAX_DELAY] : bs[ix1];
        out[j] = (1.0f - frac) * tap0 + frac * tap1;
    }

    *reinterpret_cast<float4*>(y + base) = make_float4(out[0], out[1], out[2], out[3]);
}

extern "C" void kernel_launch(void* const* d_in, const int* in_sizes, int n_in,
                              void* d_out, int out_size, void* d_ws, size_t ws_size,
                              hipStream_t stream) {
    const float* x   = (const float*)d_in[0];
    const float* dt  = (const float*)d_in[1];
    const float* buf = (const float*)d_in[2];
    float* y = (float*)d_out;

    int n4 = out_size >> 2;            // 16,000,000 / 4 = 4,000,000
    int threads = 256;
    int blocks = (n4 + threads - 1) / threads;
    tvdl_kernel<<<blocks, threads, 0, stream>>>(x, dt, buf, y, n4);
}

// Round 2
// 72.912 us; speedup vs baseline: 2.0562x; 2.0562x over previous
//
#include <hip/hip_runtime.h>

// TimeVaryingDelayLine forward.
// y[n,c,t] = (1-frac)*xpad[pos-i0] + frac*xpad[pos-i0-1],
//   xpad = concat(buffer, x), pos = MAX_DELAY + t, i0 = floor(dt).
// Key optimizations vs R1:
//  - The two taps are adjacent (ix0, ix0-1): fetch both with ONE 8B pair load
//    at ix1 (align-4; HW handles unaligned). Halves gather transactions.
//  - Region select (buffer vs x) is a branchless address cndmask; the rare
//    straddle case ix0==MAX_DELAY (~1/40000) is patched under an execz branch.
//  - XCD-contiguous block remap: each XCD gets a contiguous 1/8 of the grid
//    so its private L2 only holds its own ~1MB sliding gather window
//    (kills the 2.2x cross-XCD HBM over-fetch seen in R1).

#define MAX_DELAY 40000
#define T_LEN     1000000
#define NXCD      8

struct f2u { float a, b; };   // size 8, align 4 -> legal unaligned pair load

__global__ __launch_bounds__(256) void tvdl_kernel(
    const float* __restrict__ x,
    const float* __restrict__ dt,
    const float* __restrict__ buf,
    float* __restrict__ y,
    int n4_total, int chunk)
{
    int bid = blockIdx.x;
    int lb  = (bid & (NXCD - 1)) * chunk + (bid >> 3);  // XCD-contiguous remap
    int i   = lb * blockDim.x + threadIdx.x;
    if (i >= n4_total) return;

    int base = i << 2;                 // flat element index (multiple of 4)
    int nc   = base / T_LEN;           // series index (T_LEN % 4 == 0)
    int t0   = base - nc * T_LEN;

    const float* __restrict__ xs = x   + (size_t)nc * T_LEN;
    const float* __restrict__ bs = buf + (size_t)nc * MAX_DELAY;

    float4 d = *reinterpret_cast<const float4*>(dt + base);
    float dv[4] = {d.x, d.y, d.z, d.w};
    float out[4];

#pragma unroll
    for (int j = 0; j < 4; ++j) {
        float dvj  = dv[j];
        int   i0   = (int)dvj;             // dt >= 0 -> trunc == floor
        float frac = dvj - (float)i0;
        int   pos  = MAX_DELAY + t0 + j;
        int   ix0  = pos - i0;             // >= 2 given dt < MAX_DELAY-1
        int   ix1  = ix0 - 1;

        // pair load at xpad[ix1] covers (tap1, tap0)
        const float* p = (ix1 >= MAX_DELAY) ? (xs + (ix1 - MAX_DELAY))
                                            : (bs + ix1);
        bool straddle = (ix0 == MAX_DELAY);            // tap1 in buf, tap0 = x[0]
        if (straddle) p = bs + (MAX_DELAY - 2);        // safe in-bounds pair
        f2u pr = *reinterpret_cast<const f2u*>(p);
        float tap1 = pr.a, tap0 = pr.b;
        if (straddle) { tap1 = pr.b; tap0 = xs[0]; }   // execz nearly always

        out[j] = (1.0f - frac) * tap0 + frac * tap1;
    }

    *reinterpret_cast<float4*>(y + base) = make_float4(out[0], out[1], out[2], out[3]);
}

extern "C" void kernel_launch(void* const* d_in, const int* in_sizes, int n_in,
                              void* d_out, int out_size, void* d_ws, size_t ws_size,
                              hipStream_t stream) {
    const float* x   = (const float*)d_in[0];
    const float* dt  = (const float*)d_in[1];
    const float* buf = (const float*)d_in[2];
    float* y = (float*)d_out;

    int n4 = out_size >> 2;                         // 4,000,000
    int threads = 256;
    int blocks = (n4 + threads - 1) / threads;      // 15625
    blocks = ((blocks + NXCD - 1) / NXCD) * NXCD;   // pad to multiple of 8 (15632)
    int chunk = blocks / NXCD;                      // 1954
    tvdl_kernel<<<blocks, threads, 0, stream>>>(x, dt, buf, y, n4, chunk);
}